// Round 1
// baseline (34.111 us; speedup 1.0000x reference)
//
#include <hip/hip_runtime.h>
#include <math.h>

#define NIMG 16
#define H 512
#define W 512
#define ORI 10
#define LDS_S 67   // odd stride: bank aliasing <=2-way (free)

// ---------------- Kernel 1: per-cell 10-bin HOG histograms ----------------
// grid (8,8,16), block 256. Each block: 64x64 pixel tile = 8x8 cells.
// 4 threads per cell, each does 2 pixel rows.
__global__ __launch_bounds__(256) void hog_cells_k(const float* __restrict__ img,
                                                   float* __restrict__ cells) {
    __shared__ float tile[66 * LDS_S];
    const int n = blockIdx.z;
    const int ty0 = blockIdx.y * 64;
    const int tx0 = blockIdx.x * 64;
    const float* im = img + (size_t)n * (H * W);
    const int tid = threadIdx.x;

    // stage 66x66 halo (zero padding outside image)
    for (int i = tid; i < 66 * 66; i += 256) {
        int r = i / 66, c = i - r * 66;
        int gy = ty0 + r - 1, gx = tx0 + c - 1;
        float v = 0.0f;
        if ((unsigned)gy < (unsigned)H && (unsigned)gx < (unsigned)W)
            v = im[gy * W + gx];
        tile[r * LDS_S + c] = v;
    }
    __syncthreads();

    const int cell = tid >> 2;        // 0..63
    const int sub  = tid & 3;         // 0..3 -> rows 2*sub, 2*sub+1 of the cell
    const int cy = cell >> 3, cx = cell & 7;
    const int py0 = cy * 8 + sub * 2; // first pixel row handled by this thread
    const int px0 = cx * 8;

    // register window: LDS rows py0..py0+3 (pixel rows py0-1..py0+2 via halo),
    // cols px0..px0+9 (pixel cols px0-1..px0+8)
    float w[4][10];
    #pragma unroll
    for (int r = 0; r < 4; ++r)
        #pragma unroll
        for (int c = 0; c < 10; ++c)
            w[r][c] = tile[(py0 + r) * LDS_S + (px0 + c)];

    float acc[ORI];
    #pragma unroll
    for (int b = 0; b < ORI; ++b) acc[b] = 0.0f;

    #pragma unroll
    for (int rr = 0; rr < 2; ++rr) {
        #pragma unroll
        for (int j = 0; j < 8; ++j) {
            // correlation (XLA conv does not flip kernels)
            float gx = (w[rr  ][j] - w[rr  ][j+2])
                     + 2.0f * (w[rr+1][j] - w[rr+1][j+2])
                     + (w[rr+2][j] - w[rr+2][j+2]);
            float gy = (w[rr  ][j] + 2.0f * w[rr  ][j+1] + w[rr  ][j+2])
                     - (w[rr+2][j] + 2.0f * w[rr+2][j+1] + w[rr+2][j+2]);
            float mag = sqrtf(gx * gx + gy * gy);
            float ph  = atan2f(gx, gy);              // arctan2(gx, gy) per reference
            float p   = ph / 3.14159265358979323846f * 10.0f;
            int fi = (int)floorf(p);
            int ci = (int)ceilf(p);
            int fm = fi % ORI; fm += (fm >> 31) & ORI;   // python-style mod
            int cm = ci % ORI; cm += (cm >> 31) & ORI;
            float oneMinus = 1.0f - mag;
            // compile-time-indexed one-hot accumulate (keeps acc in VGPRs)
            #pragma unroll
            for (int b = 0; b < ORI; ++b) {
                float add = ((b == fm) ? mag : 0.0f) + ((b == cm) ? oneMinus : 0.0f);
                acc[b] += add;
            }
        }
    }

    // reduce the 4 sub-threads (consecutive lanes) and write cell means
    const int gcy = blockIdx.y * 8 + cy;
    const int gcx = blockIdx.x * 8 + cx;
    #pragma unroll
    for (int b = 0; b < ORI; ++b) {
        float v = acc[b];
        v += __shfl_xor(v, 1);
        v += __shfl_xor(v, 2);
        if (sub == 0) {
            cells[(((size_t)n * ORI + b) * 64 + gcy) * 64 + gcx] = v * 0.015625f;
        }
    }
}

// ---------------- Kernel 2: 2x2 block gather + L2-ish normalize ----------------
// one thread per (n, o, br, bc); writes 4 consecutive outputs as float4
__global__ __launch_bounds__(256) void hog_blocks_k(const float* __restrict__ cells,
                                                    float* __restrict__ out) {
    const int total = NIMG * ORI * 63 * 63;
    int idx = blockIdx.x * blockDim.x + threadIdx.x;
    if (idx >= total) return;
    int bc = idx % 63;
    int t  = idx / 63;
    int br = t % 63;
    int no = t / 63;                       // n*ORI + o
    const float* c = cells + (((size_t)no * 64 + br) * 64 + bc);
    float c00 = c[0], c01 = c[1], c10 = c[64], c11 = c[65];
    float s = ((c00 + c01) + (c10 + c11));
    float denom = sqrtf(s * s + 1e-10f);   // sqrt(sum^2 + EPS^2)
    float4 o;
    o.x = c00 / denom;
    o.y = c01 / denom;
    o.z = c10 / denom;
    o.w = c11 / denom;
    reinterpret_cast<float4*>(out)[idx] = o;
}

extern "C" void kernel_launch(void* const* d_in, const int* in_sizes, int n_in,
                              void* d_out, int out_size, void* d_ws, size_t ws_size,
                              hipStream_t stream) {
    (void)in_sizes; (void)n_in; (void)out_size; (void)ws_size;
    const float* img = (const float*)d_in[0];   // (16,1,512,512)
    // d_in[1] is the fixed sobel weight pair; constants are baked into kernel 1
    float* out   = (float*)d_out;               // (16, 10*63*63*2*2) f32
    float* cells = (float*)d_ws;                // (16,10,64,64) f32 = 2.62 MB scratch

    hog_cells_k<<<dim3(8, 8, NIMG), 256, 0, stream>>>(img, cells);

    const int total = NIMG * ORI * 63 * 63;
    hog_blocks_k<<<(total + 255) / 256, 256, 0, stream>>>(cells, out);
}